// Round 9
// baseline (113.313 us; speedup 1.0000x reference)
//
#include <hip/hip_runtime.h>

// B=16384, DIM=64, 8 coupling steps, H=8, D2=32.
// y = J^{-1} g applied analytically (triangular coupling blocks -> MLP JVPs);
// intermediate states recovered by inverting the flow from z = phi(x).
//
// R19: kill the mirror, add intra-wave ILP. R18 proved the regime: per-wave
// instruction stream is CONSTANT regardless of mirror factor, so the E=8/E=4
// mirrors multiplied total issue linearly with TLP (R10 1x -> R17 2x -> R18
// 4x work; dur 37->39->51 us; R18 VALUBusy 62% = 4x the 8 us single-copy
// VALU floor = issue-saturated on redundant work). E=16 non-redundant was
// optimal all along; its only weakness is 1024 waves = 1/SIMD (latency
// exposed). R19: each wave carries TWO independent 16-element batches
// (32 elem/wave, 512 waves, zero redundancy). The two serial chains
// interleave in-wave (same hiding as 2 waves/SIMD) and all weight/bias LDS
// loads + address math + act-masking are done ONCE per half-step for both
// batches -- overhead two mirrored waves would each pay. Grid 256 x 128thr
// = 1 block/CU, 2 waves on 2 SIMDs. Keeps: bwd H-recompute (no sHC, 42 KiB
// LDS, R18-verified), rolled loops (R17), pure-SSA state (R16), clean
// traffic. waves_per_eu(1,2) -> 256-VGPR budget for the 2-batch state.
// Layout identity (gfx950, verified m89): D (col=lane&15,row=4q+reg) ==
// B-operand (n=lane&15,k=4q+j) for K=16 -> tanh(D)->pack is per-lane, zero
// cross-lane ops.

namespace {

typedef __fp16 f16x2 __attribute__((ext_vector_type(2)));
typedef __fp16 v4h __attribute__((ext_vector_type(4)));
typedef __fp16 v8h __attribute__((ext_vector_type(8)));
typedef float f32x4 __attribute__((ext_vector_type(4)));
typedef unsigned int u32;
typedef u32 u32x2 __attribute__((ext_vector_type(2)));
typedef u32 u32x4 __attribute__((ext_vector_type(4)));

constexpr int NB = 16384;

__device__ __forceinline__ float frcp(float x) { return __builtin_amdgcn_rcpf(x); }
__device__ __forceinline__ float ftanh(float x) {
  float e = __expf(2.f * x);
  return 1.f - 2.f * frcp(e + 1.f);
}
__device__ __forceinline__ f16x2 pk(float a, float b) {
  return __builtin_amdgcn_cvt_pkrtz(a, b);
}
// Pure-SSA operand assembly: initializer-list vectors + bitcast, no memory.
__device__ __forceinline__ v8h mk8(f16x2 a, f16x2 b, f16x2 c, f16x2 d) {
  const u32x4 t = {__builtin_bit_cast(u32, a), __builtin_bit_cast(u32, b),
                   __builtin_bit_cast(u32, c), __builtin_bit_cast(u32, d)};
  return __builtin_bit_cast(v8h, t);
}
__device__ __forceinline__ v4h mk4(f16x2 a, f16x2 b) {
  const u32x2 t = {__builtin_bit_cast(u32, a), __builtin_bit_cast(u32, b)};
  return __builtin_bit_cast(v4h, t);
}

// net pair p (0..15): step i = p>>1, half = p&1 -> t-net base.
__device__ __forceinline__ int pbase(int p) {
  return ((p >> 1) << 2) + ((p & 1) << 1);
}

}  // namespace

#define MFMA32(A, B, C) __builtin_amdgcn_mfma_f32_16x16x32_f16(A, B, C, 0, 0, 0)
#define MFMA16(A, B, C) __builtin_amdgcn_mfma_f32_16x16x16f16(A, B, C, 0, 0, 0)

// ---- forward L3 block: shared A/bias load, both batches' MFMAs ----
#define L3_FWD2(P, BB, DA0, DA1, DA2, DA3, DB0, DB1, DB2, DB3)                \
  do {                                                                        \
    const bool act_ = ((BB) < 2) == (q < 2);                                  \
    v4h Ab = *(const v4h*)(LW2 + ((P)*256 + (BB)*64 + abbase));               \
    Ab = act_ ? Ab : z4;                                                      \
    const f32x4 cb = *(const f32x4*)(LB2 + ((P)*4 + (BB)) * 16 + q * 4);      \
    const f32x4 oa = MFMA16(Ab, H2va, cb);                                    \
    const f32x4 ob = MFMA16(Ab, H2vb, cb);                                    \
    DA0 = oa[0]; DA1 = oa[1]; DA2 = oa[2]; DA3 = oa[3];                       \
    DB0 = ob[0]; DB1 = ob[1]; DB2 = ob[2]; DB3 = ob[3];                       \
  } while (0)

#define FWD_UPD(S, J, W) W##S##J = fmaf(W##S##J, __expf(s##S##J), t##S##J)

// ---- forward half-step P for BOTH batches (prefixes V{a,b}*, W{a,b}*) ----
#define FWD_HALF2(P, V, W)                                                    \
  do {                                                                        \
    const v8h Bqa = mk8(pk(V##a0, V##a1), pk(V##a2, V##a3),                   \
                        pk(V##a4, V##a5), pk(V##a6, V##a7));                  \
    const v8h Bqb = mk8(pk(V##b0, V##b1), pk(V##b2, V##b3),                   \
                        pk(V##b4, V##b5), pk(V##b6, V##b7));                  \
    const v8h A0 = *(const v8h*)(LW0 + (((P)*64 + q * 16 + n) << 2));         \
    const f32x4 c0 = *(const f32x4*)(LB0 + (P)*16 + q * 4);                   \
    f32x4 d1a = MFMA32(A0, Bqa, c0);                                          \
    f32x4 d1b = MFMA32(A0, Bqb, c0);                                          \
    const f16x2 H1aa = pk(ftanh(d1a[0]), ftanh(d1a[1]));                      \
    const f16x2 H1ab = pk(ftanh(d1a[2]), ftanh(d1a[3]));                      \
    const f16x2 H1ba = pk(ftanh(d1b[0]), ftanh(d1b[1]));                      \
    const f16x2 H1bb = pk(ftanh(d1b[2]), ftanh(d1b[3]));                      \
    v4h A1 = *(const v4h*)(LW1 + ((P)*64 + a1off));                           \
    A1 = act1 ? A1 : z4;                                                      \
    const f32x4 c1 = *(const f32x4*)(LB1 + (P)*16 + q * 4);                   \
    f32x4 d2a = MFMA16(A1, mk4(H1aa, H1ab), c1);                              \
    f32x4 d2b = MFMA16(A1, mk4(H1ba, H1bb), c1);                              \
    const v4h H2va = mk4(pk(ftanh(d2a[0]), ftanh(d2a[1])),                    \
                         pk(ftanh(d2a[2]), ftanh(d2a[3])));                   \
    const v4h H2vb = mk4(pk(ftanh(d2b[0]), ftanh(d2b[1])),                    \
                         pk(ftanh(d2b[2]), ftanh(d2b[3])));                   \
    float ta0, ta1, ta2, ta3, ta4, ta5, ta6, ta7;                             \
    float sa0, sa1, sa2, sa3, sa4, sa5, sa6, sa7;                             \
    float tb0, tb1, tb2, tb3, tb4, tb5, tb6, tb7;                             \
    float sb0, sb1, sb2, sb3, sb4, sb5, sb6, sb7;                             \
    L3_FWD2(P, 0, ta0, ta1, ta2, ta3, tb0, tb1, tb2, tb3);                    \
    L3_FWD2(P, 1, ta4, ta5, ta6, ta7, tb4, tb5, tb6, tb7);                    \
    L3_FWD2(P, 2, sa0, sa1, sa2, sa3, sb0, sb1, sb2, sb3);                    \
    L3_FWD2(P, 3, sa4, sa5, sa6, sa7, sb4, sb5, sb6, sb7);                    \
    FWD_UPD(a, 0, W); FWD_UPD(a, 1, W); FWD_UPD(a, 2, W); FWD_UPD(a, 3, W);   \
    FWD_UPD(a, 4, W); FWD_UPD(a, 5, W); FWD_UPD(a, 6, W); FWD_UPD(a, 7, W);   \
    FWD_UPD(b, 0, W); FWD_UPD(b, 1, W); FWD_UPD(b, 2, W); FWD_UPD(b, 3, W);   \
    FWD_UPD(b, 4, W); FWD_UPD(b, 5, W); FWD_UPD(b, 6, W); FWD_UPD(b, 7, W);   \
  } while (0)

// ---- backward L3 block: shared A/bias load, 4 MFMAs (t/s + JVP, a/b) ----
#define L3_BWD2(P, BB, DA0, DA1, DA2, DA3, JA0, JA1, JA2, JA3,                \
                DB0, DB1, DB2, DB3, JB0, JB1, JB2, JB3)                       \
  do {                                                                        \
    const bool act_ = ((BB) < 2) == (q < 2);                                  \
    v4h Ab = *(const v4h*)(LW2 + ((P)*256 + (BB)*64 + abbase));               \
    Ab = act_ ? Ab : z4;                                                      \
    const f32x4 cb = *(const f32x4*)(LB2 + ((P)*4 + (BB)) * 16 + q * 4);      \
    const f32x4 oa = MFMA16(Ab, H2va, cb);                                    \
    const f32x4 ja = MFMA16(Ab, G2va, zc);                                    \
    const f32x4 ob = MFMA16(Ab, H2vb, cb);                                    \
    const f32x4 jb = MFMA16(Ab, G2vb, zc);                                    \
    DA0 = oa[0]; DA1 = oa[1]; DA2 = oa[2]; DA3 = oa[3];                       \
    JA0 = ja[0]; JA1 = ja[1]; JA2 = ja[2]; JA3 = ja[3];                       \
    DB0 = ob[0]; DB1 = ob[1]; DB2 = ob[2]; DB3 = ob[3];                       \
    JB0 = jb[0]; JB1 = jb[1]; JB2 = jb[2]; JB3 = jb[3];                       \
  } while (0)

#define BWD_INV(S, J, ST, DME)                                                \
  do {                                                                        \
    const float esi_ = __expf(-s##S##J);                                      \
    const float dd_ = ST##S##J - t##S##J;                                     \
    ST##S##J = dd_ * esi_;                                                    \
    DME##S##J = (DME##S##J - ut##S##J - dd_ * us##S##J) * esi_;               \
  } while (0)

// ---- backward half-step P, both batches; H1/H2 recomputed from VIN ----
#define BWD_HALF2(P, ST, DME, DOT, VIN)                                       \
  do {                                                                        \
    const v8h Bva = mk8(pk(VIN##a0, VIN##a1), pk(VIN##a2, VIN##a3),           \
                        pk(VIN##a4, VIN##a5), pk(VIN##a6, VIN##a7));          \
    const v8h Bua = mk8(pk(DOT##a0, DOT##a1), pk(DOT##a2, DOT##a3),           \
                        pk(DOT##a4, DOT##a5), pk(DOT##a6, DOT##a7));          \
    const v8h Bvb = mk8(pk(VIN##b0, VIN##b1), pk(VIN##b2, VIN##b3),           \
                        pk(VIN##b4, VIN##b5), pk(VIN##b6, VIN##b7));          \
    const v8h Bub = mk8(pk(DOT##b0, DOT##b1), pk(DOT##b2, DOT##b3),           \
                        pk(DOT##b4, DOT##b5), pk(DOT##b6, DOT##b7));          \
    const v8h A0 = *(const v8h*)(LW0 + (((P)*64 + q * 16 + n) << 2));         \
    const f32x4 c0 = *(const f32x4*)(LB0 + (P)*16 + q * 4);                   \
    f32x4 d1a = MFMA32(A0, Bva, c0);                                          \
    f32x4 d1ua = MFMA32(A0, Bua, zc);                                         \
    f32x4 d1b = MFMA32(A0, Bvb, c0);                                          \
    f32x4 d1ub = MFMA32(A0, Bub, zc);                                         \
    const float h10a = ftanh(d1a[0]), h11a = ftanh(d1a[1]);                   \
    const float h12a = ftanh(d1a[2]), h13a = ftanh(d1a[3]);                   \
    const float h10b = ftanh(d1b[0]), h11b = ftanh(d1b[1]);                   \
    const float h12b = ftanh(d1b[2]), h13b = ftanh(d1b[3]);                   \
    const f16x2 G1aa =                                                        \
        pk((1.f - h10a * h10a) * d1ua[0], (1.f - h11a * h11a) * d1ua[1]);     \
    const f16x2 G1ab =                                                        \
        pk((1.f - h12a * h12a) * d1ua[2], (1.f - h13a * h13a) * d1ua[3]);     \
    const f16x2 G1ba =                                                        \
        pk((1.f - h10b * h10b) * d1ub[0], (1.f - h11b * h11b) * d1ub[1]);     \
    const f16x2 G1bb =                                                        \
        pk((1.f - h12b * h12b) * d1ub[2], (1.f - h13b * h13b) * d1ub[3]);     \
    v4h A1 = *(const v4h*)(LW1 + ((P)*64 + a1off));                           \
    A1 = act1 ? A1 : z4;                                                      \
    const f32x4 c1 = *(const f32x4*)(LB1 + (P)*16 + q * 4);                   \
    f32x4 d2a = MFMA16(A1, mk4(pk(h10a, h11a), pk(h12a, h13a)), c1);          \
    f32x4 d2ua = MFMA16(A1, mk4(G1aa, G1ab), zc);                             \
    f32x4 d2b = MFMA16(A1, mk4(pk(h10b, h11b), pk(h12b, h13b)), c1);          \
    f32x4 d2ub = MFMA16(A1, mk4(G1ba, G1bb), zc);                             \
    const float h20a = ftanh(d2a[0]), h21a = ftanh(d2a[1]);                   \
    const float h22a = ftanh(d2a[2]), h23a = ftanh(d2a[3]);                   \
    const float h20b = ftanh(d2b[0]), h21b = ftanh(d2b[1]);                   \
    const float h22b = ftanh(d2b[2]), h23b = ftanh(d2b[3]);                   \
    const v4h H2va = mk4(pk(h20a, h21a), pk(h22a, h23a));                     \
    const v4h H2vb = mk4(pk(h20b, h21b), pk(h22b, h23b));                     \
    const v4h G2va =                                                          \
        mk4(pk((1.f - h20a * h20a) * d2ua[0], (1.f - h21a * h21a) * d2ua[1]), \
            pk((1.f - h22a * h22a) * d2ua[2], (1.f - h23a * h23a) * d2ua[3]));\
    const v4h G2vb =                                                          \
        mk4(pk((1.f - h20b * h20b) * d2ub[0], (1.f - h21b * h21b) * d2ub[1]), \
            pk((1.f - h22b * h22b) * d2ub[2], (1.f - h23b * h23b) * d2ub[3]));\
    float ta0, ta1, ta2, ta3, ta4, ta5, ta6, ta7;                             \
    float sa0, sa1, sa2, sa3, sa4, sa5, sa6, sa7;                             \
    float uta0, uta1, uta2, uta3, uta4, uta5, uta6, uta7;                     \
    float usa0, usa1, usa2, usa3, usa4, usa5, usa6, usa7;                     \
    float tb0, tb1, tb2, tb3, tb4, tb5, tb6, tb7;                             \
    float sb0, sb1, sb2, sb3, sb4, sb5, sb6, sb7;                             \
    float utb0, utb1, utb2, utb3, utb4, utb5, utb6, utb7;                     \
    float usb0, usb1, usb2, usb3, usb4, usb5, usb6, usb7;                     \
    L3_BWD2(P, 0, ta0, ta1, ta2, ta3, uta0, uta1, uta2, uta3,                 \
            tb0, tb1, tb2, tb3, utb0, utb1, utb2, utb3);                      \
    L3_BWD2(P, 1, ta4, ta5, ta6, ta7, uta4, uta5, uta6, uta7,                 \
            tb4, tb5, tb6, tb7, utb4, utb5, utb6, utb7);                      \
    L3_BWD2(P, 2, sa0, sa1, sa2, sa3, usa0, usa1, usa2, usa3,                 \
            sb0, sb1, sb2, sb3, usb0, usb1, usb2, usb3);                      \
    L3_BWD2(P, 3, sa4, sa5, sa6, sa7, usa4, usa5, usa6, usa7,                 \
            sb4, sb5, sb6, sb7, usb4, usb5, usb6, usb7);                      \
    BWD_INV(a, 0, ST, DME); BWD_INV(a, 1, ST, DME);                           \
    BWD_INV(a, 2, ST, DME); BWD_INV(a, 3, ST, DME);                           \
    BWD_INV(a, 4, ST, DME); BWD_INV(a, 5, ST, DME);                           \
    BWD_INV(a, 6, ST, DME); BWD_INV(a, 7, ST, DME);                           \
    BWD_INV(b, 0, ST, DME); BWD_INV(b, 1, ST, DME);                           \
    BWD_INV(b, 2, ST, DME); BWD_INV(b, 3, ST, DME);                           \
    BWD_INV(b, 4, ST, DME); BWD_INV(b, 5, ST, DME);                           \
    BWD_INV(b, 6, ST, DME); BWD_INV(b, 7, ST, DME);                           \
  } while (0)

// 128 threads = 2 waves; 32 elem/wave (2 batches x 16, NO mirror) = 64
// elem/block; grid 256 = 1 block/CU, 2 waves on 2 SIMDs. 512 waves total,
// zero redundant issue. LDS 42 KiB (weights only). waves_per_eu(1,2) ->
// 256-VGPR budget for the 2-batch register state.
__global__ __attribute__((amdgpu_flat_work_group_size(128, 128),
                          amdgpu_waves_per_eu(1, 2))) void nf_policy_kernel(
    const float* __restrict__ x, const float* __restrict__ xs,
    const float* __restrict__ gW0, const float* __restrict__ gb0,
    const float* __restrict__ gW1, const float* __restrict__ gb1,
    const float* __restrict__ gW2, const float* __restrict__ gb2,
    float* __restrict__ out) {
  __shared__ __align__(16) f16x2 LW0[4096];  // [16p][4q][16m][4w] A-frags L1
  __shared__ __align__(16) f16x2 LW1[1024];  // [16p][2half][8row][4kk]
  __shared__ __align__(16) f16x2 LW2[4096];  // [16p][4b][16m][4kk(2 used)]
  __shared__ __align__(16) float LB0[256];   // [16p][16m]
  __shared__ __align__(16) float LB1[256];   // [16p][16m]
  __shared__ __align__(16) float LB2[1024];  // [16p][4b][16m]

  const int tid = threadIdx.x;
  // ---- stage weights: fp32 global -> f16 LDS in MFMA A-fragment order ----
  for (int i = tid; i < 4096; i += 128) {  // LW0
    const int p = i >> 8, rem = i & 255, qq = rem >> 6, rem2 = rem & 63;
    const int mm = rem2 >> 2, w = rem2 & 3;
    const int net = pbase(p) + (mm >> 3);
    const int h = mm & 7, k0 = qq * 8 + w * 2;
    const float* src = gW0 + net * 256 + h * 32 + k0;
    LW0[i] = pk(src[0], src[1]);
  }
  for (int i = tid; i < 1024; i += 128) {  // LW1
    const int p = i >> 6, rem = i & 63, half = rem >> 5;
    const int row = (rem >> 2) & 7, kk = rem & 3;
    const int net = pbase(p) + half;
    const float* src = gW1 + net * 64 + row * 8 + kk * 2;
    LW1[i] = pk(src[0], src[1]);
  }
  for (int i = tid; i < 4096; i += 128) {  // LW2 (rows permuted)
    const int p = i >> 8, rem = i & 255, b = rem >> 6, rem2 = rem & 63;
    const int mm = rem2 >> 2, kk = rem2 & 3;
    const int net = pbase(p) + (b >> 1);
    const int d = 8 * (mm >> 2) + ((b & 1) << 2) + (mm & 3);
    const float* src = gW2 + net * 256 + d * 8 + kk * 2;
    LW2[i] = pk(src[0], src[1]);
  }
  for (int i = tid; i < 256; i += 128) {  // LB0/LB1
    const int p = i >> 4, mm = i & 15;
    const int net = pbase(p) + (mm >> 3);
    LB0[i] = gb0[net * 8 + (mm & 7)];
    LB1[i] = gb1[net * 8 + (mm & 7)];
  }
  for (int i = tid; i < 1024; i += 128) {  // LB2 (permuted like LW2 rows)
    const int p = i >> 6, b = (i >> 4) & 3, mm = i & 15;
    const int net = pbase(p) + (b >> 1);
    const int d = 8 * (mm >> 2) + ((b & 1) << 2) + (mm & 3);
    LB2[i] = gb2[net * 32 + d];
  }
  __syncthreads();

  const int lane = tid & 63;
  const int wv = tid >> 6;
  const int n = lane & 15;   // MFMA col / A row: 16 DISTINCT elements
  const int q = lane >> 4;   // quad: owns state dims 8q..8q+7
  const int eA = blockIdx.x * 64 + wv * 32 + n;  // batch a element
  const int eB = eA + 16;                        // batch b element

  const v4h z4 = {(__fp16)0.f, (__fp16)0.f, (__fp16)0.f, (__fp16)0.f};
  const f32x4 zc = {0.f, 0.f, 0.f, 0.f};
  const bool act1 = (n < 8) == (q < 2);
  const int a1off = ((n & 7) << 2) + ((q & 1) << 1) + ((n >= 8) ? 32 : 0);
  const int abbase = n * 4 + ((q & 1) << 1);

  float loa0, loa1, loa2, loa3, loa4, loa5, loa6, loa7;
  float upa0, upa1, upa2, upa3, upa4, upa5, upa6, upa7;
  float ava0, ava1, ava2, ava3, ava4, ava5, ava6, ava7;
  float bva0, bva1, bva2, bva3, bva4, bva5, bva6, bva7;
  float lob0, lob1, lob2, lob3, lob4, lob5, lob6, lob7;
  float upb0, upb1, upb2, upb3, upb4, upb5, upb6, upb7;
  float avb0, avb1, avb2, avb3, avb4, avb5, avb6, avb7;
  float bvb0, bvb1, bvb2, bvb3, bvb4, bvb5, bvb6, bvb7;
  {
    const float* xe = x + (size_t)eA * 64;
    const float* se = xs + (size_t)eA * 64;
    const float4 a0 = *(const float4*)(xe + q * 8);
    const float4 a1 = *(const float4*)(xe + q * 8 + 4);
    const float4 u0 = *(const float4*)(xe + 32 + q * 8);
    const float4 u1 = *(const float4*)(xe + 32 + q * 8 + 4);
    const float4 p0 = *(const float4*)(se + q * 8);
    const float4 p1 = *(const float4*)(se + q * 8 + 4);
    const float4 r0 = *(const float4*)(se + 32 + q * 8);
    const float4 r1 = *(const float4*)(se + 32 + q * 8 + 4);
    loa0 = a0.x; loa1 = a0.y; loa2 = a0.z; loa3 = a0.w;
    loa4 = a1.x; loa5 = a1.y; loa6 = a1.z; loa7 = a1.w;
    upa0 = u0.x; upa1 = u0.y; upa2 = u0.z; upa3 = u0.w;
    upa4 = u1.x; upa5 = u1.y; upa6 = u1.z; upa7 = u1.w;
    ava0 = -2.f * (a0.x - p0.x); ava1 = -2.f * (a0.y - p0.y);
    ava2 = -2.f * (a0.z - p0.z); ava3 = -2.f * (a0.w - p0.w);
    ava4 = -2.f * (a1.x - p1.x); ava5 = -2.f * (a1.y - p1.y);
    ava6 = -2.f * (a1.z - p1.z); ava7 = -2.f * (a1.w - p1.w);
    bva0 = -2.f * (u0.x - r0.x); bva1 = -2.f * (u0.y - r0.y);
    bva2 = -2.f * (u0.z - r0.z); bva3 = -2.f * (u0.w - r0.w);
    bva4 = -2.f * (u1.x - r1.x); bva5 = -2.f * (u1.y - r1.y);
    bva6 = -2.f * (u1.z - r1.z); bva7 = -2.f * (u1.w - r1.w);
  }
  {
    const float* xe = x + (size_t)eB * 64;
    const float* se = xs + (size_t)eB * 64;
    const float4 a0 = *(const float4*)(xe + q * 8);
    const float4 a1 = *(const float4*)(xe + q * 8 + 4);
    const float4 u0 = *(const float4*)(xe + 32 + q * 8);
    const float4 u1 = *(const float4*)(xe + 32 + q * 8 + 4);
    const float4 p0 = *(const float4*)(se + q * 8);
    const float4 p1 = *(const float4*)(se + q * 8 + 4);
    const float4 r0 = *(const float4*)(se + 32 + q * 8);
    const float4 r1 = *(const float4*)(se + 32 + q * 8 + 4);
    lob0 = a0.x; lob1 = a0.y; lob2 = a0.z; lob3 = a0.w;
    lob4 = a1.x; lob5 = a1.y; lob6 = a1.z; lob7 = a1.w;
    upb0 = u0.x; upb1 = u0.y; upb2 = u0.z; upb3 = u0.w;
    upb4 = u1.x; upb5 = u1.y; upb6 = u1.z; upb7 = u1.w;
    avb0 = -2.f * (a0.x - p0.x); avb1 = -2.f * (a0.y - p0.y);
    avb2 = -2.f * (a0.z - p0.z); avb3 = -2.f * (a0.w - p0.w);
    avb4 = -2.f * (a1.x - p1.x); avb5 = -2.f * (a1.y - p1.y);
    avb6 = -2.f * (a1.z - p1.z); avb7 = -2.f * (a1.w - p1.w);
    bvb0 = -2.f * (u0.x - r0.x); bvb1 = -2.f * (u0.y - r0.y);
    bvb2 = -2.f * (u0.z - r0.z); bvb3 = -2.f * (u0.w - r0.w);
    bvb4 = -2.f * (u1.x - r1.x); bvb5 = -2.f * (u1.y - r1.y);
    bvb6 = -2.f * (u1.z - r1.z); bvb7 = -2.f * (u1.w - r1.w);
  }

  // ---------------- forward: z = phi(x), both batches ---------------
  // even p: reads lo, updates up; odd p: reads up, updates lo.
#pragma clang loop unroll(disable)
  for (int st = 0; st < 8; ++st) {
    const int p0i = 2 * st;
    FWD_HALF2(p0i, lo, up);
    FWD_HALF2(p0i + 1, up, lo);
  }

  // ------------- backward: y = J^{-1} g, inverting the flow -------------
  // odd p first: inverts lo (input up, dual-in bv, dual-out av);
  // then even p: inverts up (input lo just reconstructed).
#pragma clang loop unroll(disable)
  for (int st = 7; st >= 0; --st) {
    const int p0i = 2 * st;
    BWD_HALF2(p0i + 1, lo, av, bv, up);
    BWD_HALF2(p0i, up, bv, av, lo);
  }

  {
    float* oe = out + (size_t)eA * 64;
    float4 v;
    v.x = ava0; v.y = ava1; v.z = ava2; v.w = ava3;
    *(float4*)(oe + q * 8) = v;
    v.x = ava4; v.y = ava5; v.z = ava6; v.w = ava7;
    *(float4*)(oe + q * 8 + 4) = v;
    v.x = bva0; v.y = bva1; v.z = bva2; v.w = bva3;
    *(float4*)(oe + 32 + q * 8) = v;
    v.x = bva4; v.y = bva5; v.z = bva6; v.w = bva7;
    *(float4*)(oe + 32 + q * 8 + 4) = v;
  }
  {
    float* oe = out + (size_t)eB * 64;
    float4 v;
    v.x = avb0; v.y = avb1; v.z = avb2; v.w = avb3;
    *(float4*)(oe + q * 8) = v;
    v.x = avb4; v.y = avb5; v.z = avb6; v.w = avb7;
    *(float4*)(oe + q * 8 + 4) = v;
    v.x = bvb0; v.y = bvb1; v.z = bvb2; v.w = bvb3;
    *(float4*)(oe + 32 + q * 8) = v;
    v.x = bvb4; v.y = bvb5; v.z = bvb6; v.w = bvb7;
    *(float4*)(oe + 32 + q * 8 + 4) = v;
  }
}

extern "C" void kernel_launch(void* const* d_in, const int* in_sizes, int n_in,
                              void* d_out, int out_size, void* d_ws,
                              size_t ws_size, hipStream_t stream) {
  const float* x  = (const float*)d_in[0];
  const float* xs = (const float*)d_in[1];
  const float* W0 = (const float*)d_in[2];
  const float* b0 = (const float*)d_in[3];
  const float* W1 = (const float*)d_in[4];
  const float* b1 = (const float*)d_in[5];
  const float* W2 = (const float*)d_in[6];
  const float* b2 = (const float*)d_in[7];
  float* out = (float*)d_out;

  dim3 grid(NB / 64);  // 256 blocks, 64 elements each (2x16 per wave)
  dim3 block(128);
  nf_policy_kernel<<<grid, block, 0, stream>>>(x, xs, W0, b0, W1, b1, W2, b2,
                                               out);
}